// Round 1
// baseline (391.128 us; speedup 1.0000x reference)
//
#include <hip/hip_runtime.h>
#include <math.h>

// Problem constants (fixed by setup_inputs):
//   x: (512, 512, 9, 9) fp32, theta: (4,) fp32, lam: (4,) fp32
//   out: (4*512, 512, 9, 9) fp32 = gabor[g,h,w] * x[co,ci,h,w]
#define NG   4
#define HW   81                    // 9*9
#define NELT (512 * 512 * 81)      // elements of x = 21,233,664
#define N4   (NELT / 4)            // float4 count   =  5,308,416
#define BLK  256
#define NBLK (N4 / BLK)            // 20,736 exact

__global__ __launch_bounds__(BLK) void gabor_mul_kernel(
    const float* __restrict__ x,
    const float* __restrict__ theta,
    const float* __restrict__ lam,
    float* __restrict__ out)
{
    __shared__ float gf[NG * HW];

    // --- Build the 4x81 Gabor table once per block ---
    // SIGMA = float32(pi); env = exp(-(fx^2+fy^2)/(2*sigma^2))  (rotation-invariant)
    // g = env * cos(2*pi * (fx*cos(th) + fy*sin(th)) * lam)
    const float PI_F = 3.14159274101257324f;       // np.float32(np.pi)
    const float INV_2SIG2 = 1.0f / (2.0f * PI_F * PI_F);
    for (int t = threadIdx.x; t < NG * HW; t += BLK) {
        int gi = t / HW;
        int p  = t - gi * HW;
        int i  = p / 9;
        int j  = p - i * 9;
        float fy = (float)(i - 4);
        float fx = (float)(j - 4);
        float th = theta[gi];
        float l  = lam[gi];
        float c  = cosf(th);
        float s  = sinf(th);
        float xr  = fx * c + fy * s;
        float env = expf(-(fx * fx + fy * fy) * INV_2SIG2);
        gf[t] = env * cosf(2.0f * PI_F * xr * l);
    }
    __syncthreads();

    // --- One float4 of x per thread; 4 output float4 stores (one per g) ---
    unsigned tid  = blockIdx.x * BLK + threadIdx.x;   // grid is exact: tid < N4
    unsigned base = tid * 4u;
    unsigned p0   = base % 81u;                       // magic-mul, no div unit
    unsigned p1 = p0 + 1u; if (p1 >= 81u) p1 -= 81u;
    unsigned p2 = p1 + 1u; if (p2 >= 81u) p2 -= 81u;
    unsigned p3 = p2 + 1u; if (p3 >= 81u) p3 -= 81u;

    const float4 xv = ((const float4*)x)[tid];

    float4* out4 = (float4*)out;
#pragma unroll
    for (int gi = 0; gi < NG; ++gi) {
        const float* gr = &gf[gi * HW];
        float4 o;
        o.x = xv.x * gr[p0];
        o.y = xv.y * gr[p1];
        o.z = xv.z * gr[p2];
        o.w = xv.w * gr[p3];
        out4[(size_t)gi * (size_t)N4 + (size_t)tid] = o;
    }
}

extern "C" void kernel_launch(void* const* d_in, const int* in_sizes, int n_in,
                              void* d_out, int out_size, void* d_ws, size_t ws_size,
                              hipStream_t stream) {
    const float* x     = (const float*)d_in[0];
    const float* theta = (const float*)d_in[1];
    const float* lam   = (const float*)d_in[2];
    float* out = (float*)d_out;

    gabor_mul_kernel<<<NBLK, BLK, 0, stream>>>(x, theta, lam, out);
}